// Round 14
// baseline (926.214 us; speedup 1.0000x reference)
//
#include <hip/hip_runtime.h>
#include <hip/hip_bf16.h>
#include <math.h>

#define NNODES 50000
#define NEDGES 800000
#define IN1 512
#define IN2 256
#define NOUT 128
#define FTOT 256   // combined feature width (two GCN branches)
#define NPB 256    // nodes per partition block (hist/fill/scan)

typedef __attribute__((ext_vector_type(4))) short short4v;
typedef __attribute__((ext_vector_type(8))) short frag_ab;
typedef __attribute__((ext_vector_type(4))) float frag_cd;

// ---------------- workspace layout (bytes) ----------------
#define OFF_XW      ((size_t)0)           // N*256 bf16 = 25,600,000
#define OFF_W1T     ((size_t)25600000)    // 128x512 bf16 [col][k]
#define OFF_W2T     ((size_t)25731072)    // 128x256 bf16 [col][k]
#define OFF_DEG     ((size_t)25796608)    // N int
#define OFF_DINV    ((size_t)25996672)    // N f32
#define OFF_ROWPTR  ((size_t)26196736)    // (N+1) int
#define OFF_CURSOR  ((size_t)26396800)    // (unused this round)
#define OFF_BSUM    ((size_t)26596864)    // 256 int
#define OFF_ADJ     ((size_t)26600960)    // E int

__device__ __forceinline__ short f2bf(float f) {
    union { float f; unsigned u; } x; x.f = f;
    unsigned r = x.u + 0x7fffu + ((x.u >> 16) & 1u);   // RNE
    return (short)(r >> 16);
}
__device__ __forceinline__ float bf2f(unsigned short u) {
    union { unsigned u; float f; } x; x.u = ((unsigned)u) << 16;
    return x.f;
}

// ---------------- D0: W transpose + f32->bf16 ----------------
__global__ __launch_bounds__(256) void wcvt_kernel(const float* __restrict__ W1, const float* __restrict__ W2,
                                                   short* __restrict__ w1t, short* __restrict__ w2t) {
    int t = blockIdx.x * 256 + threadIdx.x;
    if (t < IN1 * NOUT) {
        int c = t & 127, k = t >> 7;
        w1t[c * IN1 + k] = f2bf(W1[t]);
    } else if (t < (IN1 + IN2) * NOUT) {
        int u = t - IN1 * NOUT;
        int c = u & 127, k = u >> 7;
        w2t[c * IN2 + k] = f2bf(W2[u]);
    }
}

// ---------------- gemm: weights-stationary B in LDS ----------------
// 512-thread block = 8 waves x 32 rows = 256 rows x 128 cols. B staged into
// 64 KB LDS once per 256-K phase (2 phases mod1, 1 phase mod2) -- only 2-3
// barriers per KERNEL. Per K-step a wave issues just 4 A-loads from global
// (R13 diagnosis: 12 serialized ~600cy loads/step = 7100cy; B via LDS cuts
// the chain to 4). 16B chunks XOR-swizzled by (col&7) -> 2-way max = free.
template<int K, int COLOFF>
__device__ __forceinline__ void gemm_ldsb(const float* __restrict__ X, const short* __restrict__ Wt,
                                          short* __restrict__ xw, unsigned short* Bs,
                                          int blk, int n) {
    constexpr int NPH = K / 256;            // 2 (mod1) or 1 (mod2)
    const int tid  = threadIdx.x;
    const int wave = tid >> 6;
    const int lane = tid & 63;
    const int l15 = lane & 15, kof = lane >> 4;
    const int r0 = blk * 256 + wave * 32;
    int row0 = r0 + l15;      if (row0 >= n) row0 = n - 1;
    int row1 = r0 + 16 + l15; if (row1 >= n) row1 = n - 1;
    const float* a0p = X + (size_t)row0 * K + kof * 8;
    const float* a1p = X + (size_t)row1 * K + kof * 8;

    // B staging: thread covers col sc (0..127), quarter sq (8 x 16B chunks)
    const int sc = tid >> 2, sq = tid & 3;
    const short* wsrc = Wt + (size_t)sc * K + sq * 64;
    unsigned short* wdst = Bs + sc * 256;
    const int cswz = sc & 7;
    const int rswz = l15 & 7;

    frag_cd acc0[8], acc1[8];
    #pragma unroll
    for (int cf = 0; cf < 8; ++cf) {
        acc0[cf] = (frag_cd){0.f, 0.f, 0.f, 0.f};
        acc1[cf] = (frag_cd){0.f, 0.f, 0.f, 0.f};
    }

    auto loadA = [&](int kt, float4* m0, float4* m1) {
        m0[0] = *reinterpret_cast<const float4*>(a0p + kt);
        m0[1] = *reinterpret_cast<const float4*>(a0p + kt + 4);
        m1[0] = *reinterpret_cast<const float4*>(a1p + kt);
        m1[1] = *reinterpret_cast<const float4*>(a1p + kt + 4);
    };
    auto cvt = [&](const float4* m) -> frag_ab {
        frag_ab o;
        o[0] = f2bf(m[0].x); o[1] = f2bf(m[0].y); o[2] = f2bf(m[0].z); o[3] = f2bf(m[0].w);
        o[4] = f2bf(m[1].x); o[5] = f2bf(m[1].y); o[6] = f2bf(m[1].z); o[7] = f2bf(m[1].w);
        return o;
    };
    auto compute = [&](frag_ab fa0, frag_ab fa1, int sl) {
        __builtin_amdgcn_s_setprio(1);
        #pragma unroll
        for (int cf = 0; cf < 8; ++cf) {
            int j  = sl * 4 + kof;
            int jp = (j & 24) | ((j & 7) ^ rswz);   // read-side chunk swizzle
            frag_ab b = *reinterpret_cast<const frag_ab*>(Bs + (cf * 16 + l15) * 256 + jp * 8);
            acc0[cf] = __builtin_amdgcn_mfma_f32_16x16x32_bf16(b, fa0, acc0[cf], 0, 0, 0);
            acc1[cf] = __builtin_amdgcn_mfma_f32_16x16x32_bf16(b, fa1, acc1[cf], 0, 0, 0);
        }
        __builtin_amdgcn_s_setprio(0);
    };

    float4 pa0[2], pa1[2], qa0[2], qa1[2];

    #pragma unroll
    for (int ph = 0; ph < NPH; ++ph) {
        if (ph) __syncthreads();            // prev-phase readers done
        #pragma unroll
        for (int m = 0; m < 8; ++m) {       // stage 16B chunk, write-side swizzle
            frag_ab v = *reinterpret_cast<const frag_ab*>(wsrc + ph * 256 + m * 8);
            int jp = sq * 8 + (m ^ cswz);
            *reinterpret_cast<frag_ab*>(wdst + jp * 8) = v;
        }
        __syncthreads();                    // staged B visible

        const int kb = ph * 256;
        loadA(kb, pa0, pa1);
        #pragma unroll
        for (int sl = 0; sl < 8; sl += 2) {
            loadA(kb + (sl + 1) * 32, qa0, qa1);
            compute(cvt(pa0), cvt(pa1), sl);
            if (sl + 2 < 8) loadA(kb + (sl + 2) * 32, pa0, pa1);
            compute(cvt(qa0), cvt(qa1), sl + 1);
        }
    }

    // epilogue: lane holds rows {row0,row1}, cols kof*4 + cf*16 (+0..3)
    if (r0 + l15 < n) {
        short* dst = xw + (size_t)row0 * FTOT + COLOFF + kof * 4;
        #pragma unroll
        for (int cf = 0; cf < 8; ++cf) {
            short4v pk;
            pk[0] = f2bf(acc0[cf][0]); pk[1] = f2bf(acc0[cf][1]);
            pk[2] = f2bf(acc0[cf][2]); pk[3] = f2bf(acc0[cf][3]);
            *reinterpret_cast<short4v*>(dst + cf * 16) = pk;
        }
    }
    if (r0 + 16 + l15 < n) {
        short* dst = xw + (size_t)row1 * FTOT + COLOFF + kof * 4;
        #pragma unroll
        for (int cf = 0; cf < 8; ++cf) {
            short4v pk;
            pk[0] = f2bf(acc1[cf][0]); pk[1] = f2bf(acc1[cf][1]);
            pk[2] = f2bf(acc1[cf][2]); pk[3] = f2bf(acc1[cf][3]);
            *reinterpret_cast<short4v*>(dst + cf * 16) = pk;
        }
    }
}

// ---------------- partitioned histogram (no global atomics) ----------------
// Block owns 256 dst-nodes; scans the full (L2-resident, 3.2 MB) dst array;
// LDS counters; also emits dinv and the per-block sum (replaces scan_part).
__device__ __forceinline__ void hist_part(const int* __restrict__ ei, int* __restrict__ deg,
                                          float* __restrict__ dinv, int* __restrict__ bsum,
                                          char* smem, int hb, int n, int e) {
    int* cnt = (int*)smem;
    const int tid = threadIdx.x;
    const int base = hb * NPB;
    if (tid < NPB) cnt[tid] = 0;
    __syncthreads();
    for (int i = tid; i < e; i += 512) {
        int d = ei[e + i];
        unsigned r = (unsigned)(d - base);
        if (r < (unsigned)NPB) atomicAdd(&cnt[r], 1);
    }
    __syncthreads();
    if (tid < NPB) {
        int node = base + tid;
        if (node < n) {
            int c = cnt[tid];
            deg[node] = c;
            dinv[node] = rsqrtf((float)(c + 1));
        }
    }
    __syncthreads();
    #pragma unroll
    for (int off = 128; off > 0; off >>= 1) {
        if (tid < off) cnt[tid] += cnt[tid + off];
        __syncthreads();
    }
    if (tid == 0) bsum[hb] = cnt[0];
}

// ---------------- D1 mega: gemm1 || hist || gemm2 ----------------
__global__ __launch_bounds__(512, 2) void mega_kernel(const float* __restrict__ x1, const short* __restrict__ w1t,
                                                      const float* __restrict__ x2, const short* __restrict__ w2t,
                                                      short* __restrict__ xw, const int* __restrict__ ei,
                                                      int* __restrict__ deg, float* __restrict__ dinv,
                                                      int* __restrict__ bsum,
                                                      int n, int e, int g1b, int hbn) {
    __shared__ __align__(16) char smem[65536];
    int b = blockIdx.x;
    if (b < g1b)            gemm_ldsb<IN1, 0>(x1, w1t, xw, (unsigned short*)smem, b, n);
    else if (b < g1b + hbn) hist_part(ei, deg, dinv, bsum, smem, b - g1b, n, e);
    else                    gemm_ldsb<IN2, 128>(x2, w2t, xw, (unsigned short*)smem, b - g1b - hbn, n);
}

// ---------------- D2: rowptr scan (top-scan inlined) ----------------
__global__ __launch_bounds__(256) void scan_write_kernel(const int* __restrict__ deg, const int* __restrict__ bsum,
                                                         int* __restrict__ rowptr, int n) {
    __shared__ int s[256];
    const int tid = threadIdx.x, bid = blockIdx.x;
    // prefix over bsum[0..bid)
    int part = 0;
    for (int k = tid; k < bid; k += 256) part += bsum[k];
    s[tid] = part; __syncthreads();
    #pragma unroll
    for (int off = 128; off > 0; off >>= 1) {
        if (tid < off) s[tid] += s[tid + off];
        __syncthreads();
    }
    const int rbase = s[0];
    __syncthreads();
    // block-local inclusive scan of deg
    int i = bid * 256 + tid;
    int v = (i < n) ? deg[i] : 0;
    s[tid] = v; __syncthreads();
    for (int off = 1; off < 256; off <<= 1) {
        int u = (tid >= off) ? s[tid - off] : 0;
        __syncthreads();
        s[tid] += u;
        __syncthreads();
    }
    if (i < n) rowptr[i] = rbase + s[tid] - v;
    if (i == n - 1) rowptr[n] = rbase + s[tid];
}

// ---------------- D3: partitioned CSR fill (no global atomics) ----------------
// Block owns 256 dst-nodes; scans the full dst array; LDS cursors; adj writes
// land inside the block's contiguous ~16 KB region (L2-friendly).
__global__ __launch_bounds__(512) void fill_part_kernel(const int* __restrict__ ei, const int* __restrict__ rowptr,
                                                        int* __restrict__ adj, int n, int e) {
    __shared__ int lcur[NPB];
    const int tid = threadIdx.x, bid = blockIdx.x;
    const int base = bid * NPB;
    if (tid < NPB) {
        int node = base + tid;
        lcur[tid] = (node < n) ? rowptr[node] : 0;
    }
    __syncthreads();
    for (int i = tid; i < e; i += 512) {
        int d = ei[e + i];
        unsigned r = (unsigned)(d - base);
        if (r < (unsigned)NPB) {
            int pos = atomicAdd(&lcur[r], 1);
            adj[pos] = ei[i];
        }
    }
}

// ---------------- D4: gather + epilogue (unchanged, ~12 us) ----------------
__global__ __launch_bounds__(256) void gather_kernel(const unsigned short* __restrict__ xw,
                                                     const int* __restrict__ rowptr,
                                                     const int* __restrict__ adj,
                                                     const float* __restrict__ dinv,
                                                     const float* __restrict__ b1,
                                                     const float* __restrict__ b2,
                                                     float* __restrict__ out, int n) {
    int wid  = (int)((blockIdx.x * (size_t)blockDim.x + threadIdx.x) >> 6);
    int lane = threadIdx.x & 63;
    if (wid >= n) return;

    const ushort4* base = reinterpret_cast<const ushort4*>(xw);
    float ax = 0.f, ay = 0.f, az = 0.f, aw = 0.f;

    const int s = rowptr[wid], e = rowptr[wid + 1];
    int i = s;
    for (; i + 3 < e; i += 4) {
        int s0 = adj[i], s1 = adj[i + 1], s2 = adj[i + 2], s3 = adj[i + 3];
        float w0 = dinv[s0], w1 = dinv[s1], w2 = dinv[s2], w3 = dinv[s3];
        ushort4 v0 = base[(size_t)s0 * 64 + lane];
        ushort4 v1 = base[(size_t)s1 * 64 + lane];
        ushort4 v2 = base[(size_t)s2 * 64 + lane];
        ushort4 v3 = base[(size_t)s3 * 64 + lane];
        ax = fmaf(bf2f(v0.x), w0, fmaf(bf2f(v1.x), w1, fmaf(bf2f(v2.x), w2, fmaf(bf2f(v3.x), w3, ax))));
        ay = fmaf(bf2f(v0.y), w0, fmaf(bf2f(v1.y), w1, fmaf(bf2f(v2.y), w2, fmaf(bf2f(v3.y), w3, ay))));
        az = fmaf(bf2f(v0.z), w0, fmaf(bf2f(v1.z), w1, fmaf(bf2f(v2.z), w2, fmaf(bf2f(v3.z), w3, az))));
        aw = fmaf(bf2f(v0.w), w0, fmaf(bf2f(v1.w), w1, fmaf(bf2f(v2.w), w2, fmaf(bf2f(v3.w), w3, aw))));
    }
    for (; i < e; ++i) {
        int s0 = adj[i];
        float w0 = dinv[s0];
        ushort4 v0 = base[(size_t)s0 * 64 + lane];
        ax = fmaf(bf2f(v0.x), w0, ax); ay = fmaf(bf2f(v0.y), w0, ay);
        az = fmaf(bf2f(v0.z), w0, az); aw = fmaf(bf2f(v0.w), w0, aw);
    }
    float di = dinv[wid];
    {   // self-loop
        ushort4 v = base[(size_t)wid * 64 + lane];
        ax = fmaf(bf2f(v.x), di, ax); ay = fmaf(bf2f(v.y), di, ay);
        az = fmaf(bf2f(v.z), di, az); aw = fmaf(bf2f(v.w), di, aw);
    }
    float4 bias = (lane < 32) ? reinterpret_cast<const float4*>(b1)[lane]
                              : reinterpret_cast<const float4*>(b2)[lane - 32];
    float4 v;
    v.x = fmaxf(fmaf(ax, di, bias.x), 0.f);
    v.y = fmaxf(fmaf(ay, di, bias.y), 0.f);
    v.z = fmaxf(fmaf(az, di, bias.z), 0.f);
    v.w = fmaxf(fmaf(aw, di, bias.w), 0.f);

    float4 h;
    h.x = v.x + __shfl_xor(v.x, 32);
    h.y = v.y + __shfl_xor(v.y, 32);
    h.z = v.z + __shfl_xor(v.z, 32);
    h.w = v.w + __shfl_xor(v.w, 32);

    float m = fmaxf(fmaxf(h.x, h.y), fmaxf(h.z, h.w));
    #pragma unroll
    for (int off = 1; off <= 16; off <<= 1) m = fmaxf(m, __shfl_xor(m, off));
    float ssum = __expf(h.x - m) + __expf(h.y - m) + __expf(h.z - m) + __expf(h.w - m);
    #pragma unroll
    for (int off = 1; off <= 16; off <<= 1) ssum += __shfl_xor(ssum, off);
    float lse = m + __logf(ssum);

    if (lane < 32) {
        float4 y;
        y.x = h.x - lse; y.y = h.y - lse; y.z = h.z - lse; y.w = h.w - lse;
        reinterpret_cast<float4*>(out)[(size_t)wid * 32 + lane] = y;
    }
}

// ---------------- launcher ----------------
extern "C" void kernel_launch(void* const* d_in, const int* in_sizes, int n_in,
                              void* d_out, int out_size, void* d_ws, size_t ws_size,
                              hipStream_t stream) {
    const float* x1 = (const float*)d_in[0];
    const float* x2 = (const float*)d_in[1];
    const int*   ei = (const int*)d_in[2];
    const float* W1 = (const float*)d_in[3];
    const float* b1 = (const float*)d_in[4];
    const float* W2 = (const float*)d_in[5];
    const float* b2 = (const float*)d_in[6];
    float* out = (float*)d_out;

    const int n = in_sizes[0] / IN1;       // 50000
    const int e = in_sizes[2] / 2;         // 800000

    char* ws = (char*)d_ws;
    short* xw     = (short*)(ws + OFF_XW);
    short* w1t    = (short*)(ws + OFF_W1T);
    short* w2t    = (short*)(ws + OFF_W2T);
    int*   deg    = (int*)  (ws + OFF_DEG);
    float* dinv   = (float*)(ws + OFF_DINV);
    int*   rowptr = (int*)  (ws + OFF_ROWPTR);
    int*   bsum   = (int*)  (ws + OFF_BSUM);
    int*   adj    = (int*)  (ws + OFF_ADJ);

    const int nwb = ((IN1 + IN2) * NOUT + 255) / 256;    // 384
    const int g1b = (n + 255) / 256;       // 196 gemm1 blocks (256 rows each)
    const int g2b = g1b;                   // 196 gemm2 blocks
    const int hbn = (n + NPB - 1) / NPB;   // 196 hist blocks (256 nodes each)

    // D0: W convert
    wcvt_kernel<<<nwb, 256, 0, stream>>>(W1, W2, w1t, w2t);
    // D1: gemm1 || hist || gemm2 (one dispatch; hist also emits dinv + bsum)
    mega_kernel<<<g1b + hbn + g2b, 512, 0, stream>>>(x1, w1t, x2, w2t, xw, ei, deg, dinv, bsum, n, e, g1b, hbn);
    // D2: rowptr (top-scan inlined; scan_part/scan_top eliminated)
    scan_write_kernel<<<hbn, 256, 0, stream>>>(deg, bsum, rowptr, n);
    // D3: partitioned CSR fill
    fill_part_kernel<<<hbn, 512, 0, stream>>>(ei, rowptr, adj, n, e);
    // D4: gather + relu + add + log_softmax
    const int gb = (n + 3) / 4;
    gather_kernel<<<gb, 256, 0, stream>>>((const unsigned short*)xw, rowptr, adj, dinv, b1, b2, out, n);
}

// Round 15
// 169.751 us; speedup vs baseline: 5.4563x; 5.4563x over previous
//
#include <hip/hip_runtime.h>
#include <hip/hip_bf16.h>
#include <math.h>

#define NNODES 50000
#define NEDGES 800000
#define IN1 512
#define IN2 256
#define NOUT 128
#define FTOT 256   // combined feature width (two GCN branches)

typedef __attribute__((ext_vector_type(4))) short short4v;
typedef __attribute__((ext_vector_type(8))) short frag_ab;
typedef __attribute__((ext_vector_type(4))) float frag_cd;

// ---------------- workspace layout (bytes) ----------------
#define OFF_XW      ((size_t)0)           // N*256 bf16 = 25,600,000
#define OFF_W1T     ((size_t)25600000)    // 128x512 bf16 [col][k]
#define OFF_W2T     ((size_t)25731072)    // 128x256 bf16 [col][k]
#define OFF_DEG     ((size_t)25796608)    // N int
#define OFF_DINV    ((size_t)25996672)    // N f32
#define OFF_ROWPTR  ((size_t)26196736)    // (N+1) int
#define OFF_BSUM    ((size_t)26596864)    // 256 int
#define OFF_ADJ     ((size_t)26600960)    // E int
#define OFF_RANK    ((size_t)29800960)    // E int (edge rank within dst, from hist)

__device__ __forceinline__ short f2bf(float f) {
    union { float f; unsigned u; } x; x.f = f;
    unsigned r = x.u + 0x7fffu + ((x.u >> 16) & 1u);   // RNE
    return (short)(r >> 16);
}
__device__ __forceinline__ float bf2f(unsigned short u) {
    union { unsigned u; float f; } x; x.u = ((unsigned)u) << 16;
    return x.f;
}

// ---------------- D0: W transpose + f32->bf16 ----------------
__global__ __launch_bounds__(256) void wcvt_kernel(const float* __restrict__ W1, const float* __restrict__ W2,
                                                   short* __restrict__ w1t, short* __restrict__ w2t) {
    int t = blockIdx.x * 256 + threadIdx.x;
    if (t < IN1 * NOUT) {
        int c = t & 127, k = t >> 7;
        w1t[c * IN1 + k] = f2bf(W1[t]);
    } else if (t < (IN1 + IN2) * NOUT) {
        int u = t - IN1 * NOUT;
        int c = u & 127, k = u >> 7;
        w2t[c * IN2 + k] = f2bf(W2[u]);
    }
}

// ---------------- gemm: weights-stationary B in padded LDS ----------------
// 256-thread block = 4 waves x 32 rows = 128 rows x 128 cols. B staged into
// LDS in 128-K phases: Bs[col][136 shorts] (pad +8 -> frag reads 2-way max,
// free; R14's XOR read-swizzle caused 2.1M conflicts -- padding replaces it).
// Per K-step a wave issues only 4 A global loads (R13 diagnosis: 12
// serialized ~600cy loads/step was the wall); B comes from LDS. 34.8 KB LDS
// -> 4 blocks/CU; ~4 barriers per kernel total.
template<int K, int COLOFF>
__device__ __forceinline__ void gemm_ldsb(const float* __restrict__ X, const short* __restrict__ Wt,
                                          short* __restrict__ xw, unsigned short (*Bs)[136],
                                          int blk, int n) {
    constexpr int NPH = K / 128;            // 4 (mod1) or 2 (mod2)
    const int tid  = threadIdx.x;
    const int wave = tid >> 6;
    const int lane = tid & 63;
    const int l15 = lane & 15, kof = lane >> 4;
    const int r0 = blk * 128 + wave * 32;
    int row0 = r0 + l15;      if (row0 >= n) row0 = n - 1;
    int row1 = r0 + 16 + l15; if (row1 >= n) row1 = n - 1;
    const float* a0p = X + (size_t)row0 * K;
    const float* a1p = X + (size_t)row1 * K;

    // B staging: thread covers col sc (0..127), half sq (8 x 16B chunks)
    const int sc = tid >> 1, sq = tid & 1;
    const short* wsrc = Wt + (size_t)sc * K;

    frag_cd acc0[8], acc1[8];
    #pragma unroll
    for (int cf = 0; cf < 8; ++cf) {
        acc0[cf] = (frag_cd){0.f, 0.f, 0.f, 0.f};
        acc1[cf] = (frag_cd){0.f, 0.f, 0.f, 0.f};
    }

    auto loadA = [&](int kt, float4* m0, float4* m1) {
        m0[0] = *reinterpret_cast<const float4*>(a0p + kt + kof * 8);
        m0[1] = *reinterpret_cast<const float4*>(a0p + kt + kof * 8 + 4);
        m1[0] = *reinterpret_cast<const float4*>(a1p + kt + kof * 8);
        m1[1] = *reinterpret_cast<const float4*>(a1p + kt + kof * 8 + 4);
    };
    auto cvt = [&](const float4* m) -> frag_ab {
        frag_ab o;
        o[0] = f2bf(m[0].x); o[1] = f2bf(m[0].y); o[2] = f2bf(m[0].z); o[3] = f2bf(m[0].w);
        o[4] = f2bf(m[1].x); o[5] = f2bf(m[1].y); o[6] = f2bf(m[1].z); o[7] = f2bf(m[1].w);
        return o;
    };
    auto compute = [&](frag_ab fa0, frag_ab fa1, int sl) {
        __builtin_amdgcn_s_setprio(1);
        #pragma unroll
        for (int cf = 0; cf < 8; ++cf) {
            const unsigned short* bptr = &Bs[cf * 16 + l15][(sl * 4 + kof) * 8];
            frag_ab b = *reinterpret_cast<const frag_ab*>(bptr);
            acc0[cf] = __builtin_amdgcn_mfma_f32_16x16x32_bf16(b, fa0, acc0[cf], 0, 0, 0);
            acc1[cf] = __builtin_amdgcn_mfma_f32_16x16x32_bf16(b, fa1, acc1[cf], 0, 0, 0);
        }
        __builtin_amdgcn_s_setprio(0);
    };

    float4 pa0[2], pa1[2], qa0[2], qa1[2];

    #pragma unroll
    for (int ph = 0; ph < NPH; ++ph) {
        const int kb = ph * 128;
        if (ph) __syncthreads();            // prev-phase readers done
        #pragma unroll
        for (int m = 0; m < 8; ++m) {       // stage: 16B chunk per iter
            int chunk = sq * 8 + m;         // 0..15
            frag_ab v = *reinterpret_cast<const frag_ab*>(wsrc + kb + chunk * 8);
            *reinterpret_cast<frag_ab*>(&Bs[sc][chunk * 8]) = v;
        }
        __syncthreads();                    // staged B visible

        loadA(kb, pa0, pa1);
        #pragma unroll
        for (int sl = 0; sl < 4; sl += 2) {
            loadA(kb + (sl + 1) * 32, qa0, qa1);
            compute(cvt(pa0), cvt(pa1), sl);
            if (sl + 2 < 4) loadA(kb + (sl + 2) * 32, pa0, pa1);
            compute(cvt(qa0), cvt(qa1), sl + 1);
        }
    }

    // epilogue: lane holds rows {row0,row1}, cols kof*4 + cf*16 (+0..3)
    if (r0 + l15 < n) {
        short* dst = xw + (size_t)row0 * FTOT + COLOFF + kof * 4;
        #pragma unroll
        for (int cf = 0; cf < 8; ++cf) {
            short4v pk;
            pk[0] = f2bf(acc0[cf][0]); pk[1] = f2bf(acc0[cf][1]);
            pk[2] = f2bf(acc0[cf][2]); pk[3] = f2bf(acc0[cf][3]);
            *reinterpret_cast<short4v*>(dst + cf * 16) = pk;
        }
    }
    if (r0 + 16 + l15 < n) {
        short* dst = xw + (size_t)row1 * FTOT + COLOFF + kof * 4;
        #pragma unroll
        for (int cf = 0; cf < 8; ++cf) {
            short4v pk;
            pk[0] = f2bf(acc1[cf][0]); pk[1] = f2bf(acc1[cf][1]);
            pk[2] = f2bf(acc1[cf][2]); pk[3] = f2bf(acc1[cf][3]);
            *reinterpret_cast<short4v*>(dst + cf * 16) = pk;
        }
    }
}

// D1: gemm1 blocks || hist blocks. hist stores each edge's RANK (the returned
// old count) so fill needs NO atomics. Strict role guards (R8 lesson).
__global__ __launch_bounds__(256, 2) void g1_kernel(const float* __restrict__ x1, const short* __restrict__ w1t,
                                                    short* __restrict__ xw, const int* __restrict__ ei,
                                                    int* __restrict__ deg, int* __restrict__ rank,
                                                    int n, int e, int g1b, int nhb) {
    __shared__ __align__(16) unsigned short Bs[128][136];   // 34,816 B
    int b = blockIdx.x;
    if (b < g1b) {
        gemm_ldsb<IN1, 0>(x1, w1t, xw, Bs, b, n);
    } else if (b < g1b + nhb) {
        for (int i = (b - g1b) * 256 + threadIdx.x; i < e; i += nhb * 256) {
            int old = atomicAdd(&deg[ei[e + i]], 1);
            rank[i] = old;
        }
    }
}

// D3: gemm2 blocks || fill blocks (atomic-free: pos = rowptr[dst] + rank[i])
__global__ __launch_bounds__(256, 2) void g2_kernel(const float* __restrict__ x2, const short* __restrict__ w2t,
                                                    short* __restrict__ xw, const int* __restrict__ ei,
                                                    const int* __restrict__ rowptr, const int* __restrict__ rank,
                                                    int* __restrict__ adj,
                                                    int n, int e, int g2b, int nfb) {
    __shared__ __align__(16) unsigned short Bs[128][136];
    int b = blockIdx.x;
    if (b < g2b) {
        gemm_ldsb<IN2, 128>(x2, w2t, xw, Bs, b, n);
    } else if (b < g2b + nfb) {
        for (int i = (b - g2b) * 256 + threadIdx.x; i < e; i += nfb * 256) {
            int dst = ei[e + i];
            adj[rowptr[dst] + rank[i]] = ei[i];
        }
    }
}

// ---------------- scans (R10-proven trio; rowptr only, no cursor) ------------
__global__ __launch_bounds__(256) void scan_part_kernel(const int* __restrict__ deg, float* __restrict__ dinv,
                                                        int* __restrict__ bsum, int n) {
    __shared__ int s[256];
    int t = threadIdx.x;
    int i = blockIdx.x * 256 + t;
    int v = (i < n) ? deg[i] : 0;
    if (i < n) dinv[i] = rsqrtf((float)(v + 1));
    s[t] = v; __syncthreads();
    #pragma unroll
    for (int off = 128; off > 0; off >>= 1) {
        if (t < off) s[t] += s[t + off];
        __syncthreads();
    }
    if (t == 0) bsum[blockIdx.x] = s[0];
}

__global__ __launch_bounds__(256) void scan_top_kernel(int* __restrict__ bsum, int nb) {
    __shared__ int s[256];
    int t = threadIdx.x;
    int v = (t < nb) ? bsum[t] : 0;
    s[t] = v; __syncthreads();
    for (int off = 1; off < 256; off <<= 1) {
        int u = (t >= off) ? s[t - off] : 0;
        __syncthreads();
        s[t] += u;
        __syncthreads();
    }
    if (t < nb) bsum[t] = s[t] - v;
}

__global__ __launch_bounds__(256) void scan_write_kernel(const int* __restrict__ deg, const int* __restrict__ bsum,
                                                         int* __restrict__ rowptr, int n) {
    __shared__ int s[256];
    int t = threadIdx.x;
    int i = blockIdx.x * 256 + t;
    int v = (i < n) ? deg[i] : 0;
    s[t] = v; __syncthreads();
    for (int off = 1; off < 256; off <<= 1) {
        int u = (t >= off) ? s[t - off] : 0;
        __syncthreads();
        s[t] += u;
        __syncthreads();
    }
    int base = bsum[blockIdx.x];
    if (i < n) rowptr[i] = base + s[t] - v;
    if (i == n - 1) rowptr[n] = base + s[t];
}

// ---------------- D4: gather + epilogue (unchanged) ----------------
__global__ __launch_bounds__(256) void gather_kernel(const unsigned short* __restrict__ xw,
                                                     const int* __restrict__ rowptr,
                                                     const int* __restrict__ adj,
                                                     const float* __restrict__ dinv,
                                                     const float* __restrict__ b1,
                                                     const float* __restrict__ b2,
                                                     float* __restrict__ out, int n) {
    int wid  = (int)((blockIdx.x * (size_t)blockDim.x + threadIdx.x) >> 6);
    int lane = threadIdx.x & 63;
    if (wid >= n) return;

    const ushort4* base = reinterpret_cast<const ushort4*>(xw);
    float ax = 0.f, ay = 0.f, az = 0.f, aw = 0.f;

    const int s = rowptr[wid], e = rowptr[wid + 1];
    int i = s;
    for (; i + 3 < e; i += 4) {
        int s0 = adj[i], s1 = adj[i + 1], s2 = adj[i + 2], s3 = adj[i + 3];
        float w0 = dinv[s0], w1 = dinv[s1], w2 = dinv[s2], w3 = dinv[s3];
        ushort4 v0 = base[(size_t)s0 * 64 + lane];
        ushort4 v1 = base[(size_t)s1 * 64 + lane];
        ushort4 v2 = base[(size_t)s2 * 64 + lane];
        ushort4 v3 = base[(size_t)s3 * 64 + lane];
        ax = fmaf(bf2f(v0.x), w0, fmaf(bf2f(v1.x), w1, fmaf(bf2f(v2.x), w2, fmaf(bf2f(v3.x), w3, ax))));
        ay = fmaf(bf2f(v0.y), w0, fmaf(bf2f(v1.y), w1, fmaf(bf2f(v2.y), w2, fmaf(bf2f(v3.y), w3, ay))));
        az = fmaf(bf2f(v0.z), w0, fmaf(bf2f(v1.z), w1, fmaf(bf2f(v2.z), w2, fmaf(bf2f(v3.z), w3, az))));
        aw = fmaf(bf2f(v0.w), w0, fmaf(bf2f(v1.w), w1, fmaf(bf2f(v2.w), w2, fmaf(bf2f(v3.w), w3, aw))));
    }
    for (; i < e; ++i) {
        int s0 = adj[i];
        float w0 = dinv[s0];
        ushort4 v0 = base[(size_t)s0 * 64 + lane];
        ax = fmaf(bf2f(v0.x), w0, ax); ay = fmaf(bf2f(v0.y), w0, ay);
        az = fmaf(bf2f(v0.z), w0, az); aw = fmaf(bf2f(v0.w), w0, aw);
    }
    float di = dinv[wid];
    {   // self-loop
        ushort4 v = base[(size_t)wid * 64 + lane];
        ax = fmaf(bf2f(v.x), di, ax); ay = fmaf(bf2f(v.y), di, ay);
        az = fmaf(bf2f(v.z), di, az); aw = fmaf(bf2f(v.w), di, aw);
    }
    float4 bias = (lane < 32) ? reinterpret_cast<const float4*>(b1)[lane]
                              : reinterpret_cast<const float4*>(b2)[lane - 32];
    float4 v;
    v.x = fmaxf(fmaf(ax, di, bias.x), 0.f);
    v.y = fmaxf(fmaf(ay, di, bias.y), 0.f);
    v.z = fmaxf(fmaf(az, di, bias.z), 0.f);
    v.w = fmaxf(fmaf(aw, di, bias.w), 0.f);

    float4 h;
    h.x = v.x + __shfl_xor(v.x, 32);
    h.y = v.y + __shfl_xor(v.y, 32);
    h.z = v.z + __shfl_xor(v.z, 32);
    h.w = v.w + __shfl_xor(v.w, 32);

    float m = fmaxf(fmaxf(h.x, h.y), fmaxf(h.z, h.w));
    #pragma unroll
    for (int off = 1; off <= 16; off <<= 1) m = fmaxf(m, __shfl_xor(m, off));
    float ssum = __expf(h.x - m) + __expf(h.y - m) + __expf(h.z - m) + __expf(h.w - m);
    #pragma unroll
    for (int off = 1; off <= 16; off <<= 1) ssum += __shfl_xor(ssum, off);
    float lse = m + __logf(ssum);

    if (lane < 32) {
        float4 y;
        y.x = h.x - lse; y.y = h.y - lse; y.z = h.z - lse; y.w = h.w - lse;
        reinterpret_cast<float4*>(out)[(size_t)wid * 32 + lane] = y;
    }
}

// ---------------- launcher ----------------
extern "C" void kernel_launch(void* const* d_in, const int* in_sizes, int n_in,
                              void* d_out, int out_size, void* d_ws, size_t ws_size,
                              hipStream_t stream) {
    const float* x1 = (const float*)d_in[0];
    const float* x2 = (const float*)d_in[1];
    const int*   ei = (const int*)d_in[2];
    const float* W1 = (const float*)d_in[3];
    const float* b1 = (const float*)d_in[4];
    const float* W2 = (const float*)d_in[5];
    const float* b2 = (const float*)d_in[6];
    float* out = (float*)d_out;

    const int n = in_sizes[0] / IN1;       // 50000
    const int e = in_sizes[2] / 2;         // 800000

    char* ws = (char*)d_ws;
    short* xw     = (short*)(ws + OFF_XW);
    short* w1t    = (short*)(ws + OFF_W1T);
    short* w2t    = (short*)(ws + OFF_W2T);
    int*   deg    = (int*)  (ws + OFF_DEG);
    float* dinv   = (float*)(ws + OFF_DINV);
    int*   rowptr = (int*)  (ws + OFF_ROWPTR);
    int*   bsum   = (int*)  (ws + OFF_BSUM);
    int*   adj    = (int*)  (ws + OFF_ADJ);
    int*   rank   = (int*)  (ws + OFF_RANK);

    const int nb_n = (n + 255) / 256;      // 196
    const int nwb  = ((IN1 + IN2) * NOUT + 255) / 256;   // 384
    const int g1b  = (n + 127) / 128;      // 391 gemm1 blocks (128 rows each)
    const int g2b  = g1b;                  // 391 gemm2 blocks
    const int nhb  = 391;                  // hist blocks (grid-stride)
    const int nfb  = 391;                  // fill blocks (grid-stride)

    // D0: zero deg + W convert
    hipMemsetAsync(deg, 0, (size_t)n * sizeof(int), stream);
    wcvt_kernel<<<nwb, 256, 0, stream>>>(W1, W2, w1t, w2t);
    // D1: gemm1 || hist(+rank)
    g1_kernel<<<g1b + nhb, 256, 0, stream>>>(x1, w1t, xw, ei, deg, rank, n, e, g1b, nhb);
    // D2: scans -> dinv, rowptr
    scan_part_kernel<<<nb_n, 256, 0, stream>>>(deg, dinv, bsum, n);
    scan_top_kernel<<<1, 256, 0, stream>>>(bsum, nb_n);
    scan_write_kernel<<<nb_n, 256, 0, stream>>>(deg, bsum, rowptr, n);
    // D3: gemm2 || fill (atomic-free)
    g2_kernel<<<g2b + nfb, 256, 0, stream>>>(x2, w2t, xw, ei, rowptr, rank, adj, n, e, g2b, nfb);
    // D4: gather + relu + add + log_softmax
    const int gb = (n + 3) / 4;
    gather_kernel<<<gb, 256, 0, stream>>>((const unsigned short*)xw, rowptr, adj, dinv, b1, b2, out, n);
}

// Round 16
// 153.847 us; speedup vs baseline: 6.0204x; 1.1034x over previous
//
#include <hip/hip_runtime.h>
#include <hip/hip_bf16.h>
#include <math.h>

#define NNODES 50000
#define NEDGES 800000
#define IN1 512
#define IN2 256
#define NOUT 128
#define FTOT 256   // combined feature width (two GCN branches)

typedef __attribute__((ext_vector_type(4))) short short4v;
typedef __attribute__((ext_vector_type(8))) short frag_ab;
typedef __attribute__((ext_vector_type(4))) float frag_cd;

// ---------------- workspace layout (bytes) ----------------
#define OFF_XW      ((size_t)0)           // N*256 bf16 = 25,600,000
#define OFF_W1T     ((size_t)25600000)    // 128x512 bf16 [col][k]
#define OFF_W2T     ((size_t)25731072)    // 128x256 bf16 [col][k]
#define OFF_DEG     ((size_t)25796608)    // N int
#define OFF_DINV    ((size_t)25996672)    // N f32
#define OFF_ROWPTR  ((size_t)26196736)    // (N+1) int
#define OFF_BSUM    ((size_t)26596864)    // 256 int
#define OFF_ADJ     ((size_t)26600960)    // E int
#define OFF_RANK    ((size_t)29800960)    // E int (edge rank within dst, from hist)

__device__ __forceinline__ short f2bf(float f) {
    union { float f; unsigned u; } x; x.f = f;
    unsigned r = x.u + 0x7fffu + ((x.u >> 16) & 1u);   // RNE
    return (short)(r >> 16);
}
__device__ __forceinline__ float bf2f(unsigned short u) {
    union { unsigned u; float f; } x; x.u = ((unsigned)u) << 16;
    return x.f;
}

// ---------------- D0: W transpose + f32->bf16 ----------------
__global__ __launch_bounds__(256) void wcvt_kernel(const float* __restrict__ W1, const float* __restrict__ W2,
                                                   short* __restrict__ w1t, short* __restrict__ w2t) {
    int t = blockIdx.x * 256 + threadIdx.x;
    if (t < IN1 * NOUT) {
        int c = t & 127, k = t >> 7;
        w1t[c * IN1 + k] = f2bf(W1[t]);
    } else if (t < (IN1 + IN2) * NOUT) {
        int u = t - IN1 * NOUT;
        int c = u & 127, k = u >> 7;
        w2t[c * IN2 + k] = f2bf(W2[u]);
    }
}

// ---------------- gemm: B in padded LDS, 16-row waves (acc = 32 VGPR) --------
// R15 diagnosis: VGPR_Count=64 == the 32-row wave's accumulator alone, so the
// allocator serialized every A-load (4 x ~950cy = 3830cy/step, measured).
// Halving the wave tile to 16 rows halves acc to 32 VGPR -> headroom for
// in-flight loads, and 8 waves/block at 512 threads doubles waves/SIMD.
// B staged per 128-K phase into Bs[col][136] (pad +8: frag reads 2-way, free).
template<int K, int COLOFF>
__device__ __forceinline__ void gemm_ldsb16(const float* __restrict__ X, const short* __restrict__ Wt,
                                            short* __restrict__ xw, unsigned short (*Bs)[136],
                                            int blk, int n) {
    constexpr int NPH = K / 128;            // 4 (mod1) or 2 (mod2)
    const int tid  = threadIdx.x;
    const int wave = tid >> 6;              // 0..7
    const int lane = tid & 63;
    const int l15 = lane & 15, kof = lane >> 4;
    int row = blk * 128 + wave * 16 + l15;
    const bool rok = (row < n);
    if (!rok) row = n - 1;
    const float* ap = X + (size_t)row * K;

    // B staging: 4 threads per col; thread stages 4 x 16B chunks
    const int sc = tid >> 2, sq = tid & 3;
    const short* wsrc = Wt + (size_t)sc * K;

    frag_cd acc[8];
    #pragma unroll
    for (int cf = 0; cf < 8; ++cf) acc[cf] = (frag_cd){0.f, 0.f, 0.f, 0.f};

    auto loadA = [&](int kt, float4* m) {
        m[0] = *reinterpret_cast<const float4*>(ap + kt + kof * 8);
        m[1] = *reinterpret_cast<const float4*>(ap + kt + kof * 8 + 4);
    };
    auto cvt = [&](const float4* m) -> frag_ab {
        frag_ab o;
        o[0] = f2bf(m[0].x); o[1] = f2bf(m[0].y); o[2] = f2bf(m[0].z); o[3] = f2bf(m[0].w);
        o[4] = f2bf(m[1].x); o[5] = f2bf(m[1].y); o[6] = f2bf(m[1].z); o[7] = f2bf(m[1].w);
        return o;
    };
    auto compute = [&](frag_ab fa, int sl) {
        __builtin_amdgcn_s_setprio(1);
        #pragma unroll
        for (int cf = 0; cf < 8; ++cf) {
            frag_ab b = *reinterpret_cast<const frag_ab*>(&Bs[cf * 16 + l15][(sl * 4 + kof) * 8]);
            acc[cf] = __builtin_amdgcn_mfma_f32_16x16x32_bf16(b, fa, acc[cf], 0, 0, 0);
        }
        __builtin_amdgcn_s_setprio(0);
    };

    float4 pa[2], qa[2];

    #pragma unroll
    for (int ph = 0; ph < NPH; ++ph) {
        const int kb = ph * 128;
        if (ph) __syncthreads();            // prev-phase readers done
        #pragma unroll
        for (int j = 0; j < 4; ++j) {       // stage 4 x 16B chunks (col sc)
            int chunk = sq * 4 + j;         // 0..15
            frag_ab v = *reinterpret_cast<const frag_ab*>(wsrc + kb + chunk * 8);
            *reinterpret_cast<frag_ab*>(&Bs[sc][chunk * 8]) = v;
        }
        __syncthreads();                    // staged B visible

        loadA(kb, pa);
        #pragma unroll
        for (int sl = 0; sl < 4; sl += 2) {
            loadA(kb + (sl + 1) * 32, qa);
            compute(cvt(pa), sl);
            if (sl + 2 < 4) loadA(kb + (sl + 2) * 32, pa);
            compute(cvt(qa), sl + 1);
        }
    }

    // epilogue: lane holds row, cols kof*4 + cf*16 (+0..3)
    if (rok) {
        short* dst = xw + (size_t)row * FTOT + COLOFF + kof * 4;
        #pragma unroll
        for (int cf = 0; cf < 8; ++cf) {
            short4v pk;
            pk[0] = f2bf(acc[cf][0]); pk[1] = f2bf(acc[cf][1]);
            pk[2] = f2bf(acc[cf][2]); pk[3] = f2bf(acc[cf][3]);
            *reinterpret_cast<short4v*>(dst + cf * 16) = pk;
        }
    }
}

// D1 mega: gemm1 || gemm2 || hist(+rank) -- all mutually independent.
// 1173 blocks x 512 thr ~ 4.6 blocks/CU x 8 waves ~ 29 waves/CU (~7/SIMD),
// the highest TLP of any round. Strict role guards (R8 lesson).
__global__ __launch_bounds__(512, 2) void mega_kernel(const float* __restrict__ x1, const short* __restrict__ w1t,
                                                      const float* __restrict__ x2, const short* __restrict__ w2t,
                                                      short* __restrict__ xw, const int* __restrict__ ei,
                                                      int* __restrict__ deg, int* __restrict__ rank,
                                                      int n, int e, int g1b, int g2b, int nhb) {
    __shared__ __align__(16) unsigned short Bs[128][136];   // 34,816 B
    int b = blockIdx.x;
    if (b < g1b) {
        gemm_ldsb16<IN1, 0>(x1, w1t, xw, Bs, b, n);
    } else if (b < g1b + g2b) {
        gemm_ldsb16<IN2, 128>(x2, w2t, xw, Bs, b - g1b, n);
    } else if (b < g1b + g2b + nhb) {
        for (int i = (b - g1b - g2b) * 512 + threadIdx.x; i < e; i += nhb * 512) {
            int old = atomicAdd(&deg[ei[e + i]], 1);
            rank[i] = old;
        }
    }
}

// ---------------- scans (proven trio) ----------------
__global__ __launch_bounds__(256) void scan_part_kernel(const int* __restrict__ deg, float* __restrict__ dinv,
                                                        int* __restrict__ bsum, int n) {
    __shared__ int s[256];
    int t = threadIdx.x;
    int i = blockIdx.x * 256 + t;
    int v = (i < n) ? deg[i] : 0;
    if (i < n) dinv[i] = rsqrtf((float)(v + 1));
    s[t] = v; __syncthreads();
    #pragma unroll
    for (int off = 128; off > 0; off >>= 1) {
        if (t < off) s[t] += s[t + off];
        __syncthreads();
    }
    if (t == 0) bsum[blockIdx.x] = s[0];
}

__global__ __launch_bounds__(256) void scan_top_kernel(int* __restrict__ bsum, int nb) {
    __shared__ int s[256];
    int t = threadIdx.x;
    int v = (t < nb) ? bsum[t] : 0;
    s[t] = v; __syncthreads();
    for (int off = 1; off < 256; off <<= 1) {
        int u = (t >= off) ? s[t - off] : 0;
        __syncthreads();
        s[t] += u;
        __syncthreads();
    }
    if (t < nb) bsum[t] = s[t] - v;
}

__global__ __launch_bounds__(256) void scan_write_kernel(const int* __restrict__ deg, const int* __restrict__ bsum,
                                                         int* __restrict__ rowptr, int n) {
    __shared__ int s[256];
    int t = threadIdx.x;
    int i = blockIdx.x * 256 + t;
    int v = (i < n) ? deg[i] : 0;
    s[t] = v; __syncthreads();
    for (int off = 1; off < 256; off <<= 1) {
        int u = (t >= off) ? s[t - off] : 0;
        __syncthreads();
        s[t] += u;
        __syncthreads();
    }
    int base = bsum[blockIdx.x];
    if (i < n) rowptr[i] = base + s[t] - v;
    if (i == n - 1) rowptr[n] = base + s[t];
}

// ---------------- D3: rank-based CSR fill (atomic-free, ~8 us) ----------------
__global__ __launch_bounds__(256) void fill_rank_kernel(const int* __restrict__ ei, const int* __restrict__ rowptr,
                                                        const int* __restrict__ rank, int* __restrict__ adj, int e) {
    int i = blockIdx.x * 256 + threadIdx.x;
    if (i < e) {
        int dst = ei[e + i];
        adj[rowptr[dst] + rank[i]] = ei[i];
    }
}

// ---------------- D4: gather + epilogue (unchanged) ----------------
__global__ __launch_bounds__(256) void gather_kernel(const unsigned short* __restrict__ xw,
                                                     const int* __restrict__ rowptr,
                                                     const int* __restrict__ adj,
                                                     const float* __restrict__ dinv,
                                                     const float* __restrict__ b1,
                                                     const float* __restrict__ b2,
                                                     float* __restrict__ out, int n) {
    int wid  = (int)((blockIdx.x * (size_t)blockDim.x + threadIdx.x) >> 6);
    int lane = threadIdx.x & 63;
    if (wid >= n) return;

    const ushort4* base = reinterpret_cast<const ushort4*>(xw);
    float ax = 0.f, ay = 0.f, az = 0.f, aw = 0.f;

    const int s = rowptr[wid], e = rowptr[wid + 1];
    int i = s;
    for (; i + 3 < e; i += 4) {
        int s0 = adj[i], s1 = adj[i + 1], s2 = adj[i + 2], s3 = adj[i + 3];
        float w0 = dinv[s0], w1 = dinv[s1], w2 = dinv[s2], w3 = dinv[s3];
        ushort4 v0 = base[(size_t)s0 * 64 + lane];
        ushort4 v1 = base[(size_t)s1 * 64 + lane];
        ushort4 v2 = base[(size_t)s2 * 64 + lane];
        ushort4 v3 = base[(size_t)s3 * 64 + lane];
        ax = fmaf(bf2f(v0.x), w0, fmaf(bf2f(v1.x), w1, fmaf(bf2f(v2.x), w2, fmaf(bf2f(v3.x), w3, ax))));
        ay = fmaf(bf2f(v0.y), w0, fmaf(bf2f(v1.y), w1, fmaf(bf2f(v2.y), w2, fmaf(bf2f(v3.y), w3, ay))));
        az = fmaf(bf2f(v0.z), w0, fmaf(bf2f(v1.z), w1, fmaf(bf2f(v2.z), w2, fmaf(bf2f(v3.z), w3, az))));
        aw = fmaf(bf2f(v0.w), w0, fmaf(bf2f(v1.w), w1, fmaf(bf2f(v2.w), w2, fmaf(bf2f(v3.w), w3, aw))));
    }
    for (; i < e; ++i) {
        int s0 = adj[i];
        float w0 = dinv[s0];
        ushort4 v0 = base[(size_t)s0 * 64 + lane];
        ax = fmaf(bf2f(v0.x), w0, ax); ay = fmaf(bf2f(v0.y), w0, ay);
        az = fmaf(bf2f(v0.z), w0, az); aw = fmaf(bf2f(v0.w), w0, aw);
    }
    float di = dinv[wid];
    {   // self-loop
        ushort4 v = base[(size_t)wid * 64 + lane];
        ax = fmaf(bf2f(v.x), di, ax); ay = fmaf(bf2f(v.y), di, ay);
        az = fmaf(bf2f(v.z), di, az); aw = fmaf(bf2f(v.w), di, aw);
    }
    float4 bias = (lane < 32) ? reinterpret_cast<const float4*>(b1)[lane]
                              : reinterpret_cast<const float4*>(b2)[lane - 32];
    float4 v;
    v.x = fmaxf(fmaf(ax, di, bias.x), 0.f);
    v.y = fmaxf(fmaf(ay, di, bias.y), 0.f);
    v.z = fmaxf(fmaf(az, di, bias.z), 0.f);
    v.w = fmaxf(fmaf(aw, di, bias.w), 0.f);

    float4 h;
    h.x = v.x + __shfl_xor(v.x, 32);
    h.y = v.y + __shfl_xor(v.y, 32);
    h.z = v.z + __shfl_xor(v.z, 32);
    h.w = v.w + __shfl_xor(v.w, 32);

    float m = fmaxf(fmaxf(h.x, h.y), fmaxf(h.z, h.w));
    #pragma unroll
    for (int off = 1; off <= 16; off <<= 1) m = fmaxf(m, __shfl_xor(m, off));
    float ssum = __expf(h.x - m) + __expf(h.y - m) + __expf(h.z - m) + __expf(h.w - m);
    #pragma unroll
    for (int off = 1; off <= 16; off <<= 1) ssum += __shfl_xor(ssum, off);
    float lse = m + __logf(ssum);

    if (lane < 32) {
        float4 y;
        y.x = h.x - lse; y.y = h.y - lse; y.z = h.z - lse; y.w = h.w - lse;
        reinterpret_cast<float4*>(out)[(size_t)wid * 32 + lane] = y;
    }
}

// ---------------- launcher ----------------
extern "C" void kernel_launch(void* const* d_in, const int* in_sizes, int n_in,
                              void* d_out, int out_size, void* d_ws, size_t ws_size,
                              hipStream_t stream) {
    const float* x1 = (const float*)d_in[0];
    const float* x2 = (const float*)d_in[1];
    const int*   ei = (const int*)d_in[2];
    const float* W1 = (const float*)d_in[3];
    const float* b1 = (const float*)d_in[4];
    const float* W2 = (const float*)d_in[5];
    const float* b2 = (const float*)d_in[6];
    float* out = (float*)d_out;

    const int n = in_sizes[0] / IN1;       // 50000
    const int e = in_sizes[2] / 2;         // 800000

    char* ws = (char*)d_ws;
    short* xw     = (short*)(ws + OFF_XW);
    short* w1t    = (short*)(ws + OFF_W1T);
    short* w2t    = (short*)(ws + OFF_W2T);
    int*   deg    = (int*)  (ws + OFF_DEG);
    float* dinv   = (float*)(ws + OFF_DINV);
    int*   rowptr = (int*)  (ws + OFF_ROWPTR);
    int*   bsum   = (int*)  (ws + OFF_BSUM);
    int*   adj    = (int*)  (ws + OFF_ADJ);
    int*   rank   = (int*)  (ws + OFF_RANK);

    const int nb_n = (n + 255) / 256;      // 196
    const int nb_e = (e + 255) / 256;      // 3125
    const int nwb  = ((IN1 + IN2) * NOUT + 255) / 256;   // 384
    const int g1b  = (n + 127) / 128;      // 391 gemm1 blocks (128 rows, 8 waves)
    const int g2b  = g1b;                  // 391 gemm2 blocks
    const int nhb  = 391;                  // hist blocks (grid-stride, 512 thr)

    // D0: zero deg + W convert
    hipMemsetAsync(deg, 0, (size_t)n * sizeof(int), stream);
    wcvt_kernel<<<nwb, 256, 0, stream>>>(W1, W2, w1t, w2t);
    // D1: gemm1 || gemm2 || hist(+rank) -- max TLP
    mega_kernel<<<g1b + g2b + nhb, 512, 0, stream>>>(x1, w1t, x2, w2t, xw, ei, deg, rank, n, e, g1b, g2b, nhb);
    // D2: scans -> dinv, rowptr
    scan_part_kernel<<<nb_n, 256, 0, stream>>>(deg, dinv, bsum, n);
    scan_top_kernel<<<1, 256, 0, stream>>>(bsum, nb_n);
    scan_write_kernel<<<nb_n, 256, 0, stream>>>(deg, bsum, rowptr, n);
    // D3: rank-based CSR fill (atomic-free)
    fill_rank_kernel<<<nb_e, 256, 0, stream>>>(ei, rowptr, rank, adj, e);
    // D4: gather + relu + add + log_softmax
    const int gb = (n + 3) / 4;
    gather_kernel<<<gb, 256, 0, stream>>>((const unsigned short*)xw, rowptr, adj, dinv, b1, b2, out, n);
}